// Round 1
// baseline (128.405 us; speedup 1.0000x reference)
//
#include <hip/hip_runtime.h>

// SSIM fused kernel, MI355X (gfx950).
// Inputs: pred, target fp32 [16,3,512,512]. Output: scalar mean of ssim_map.
// Design:
//  - Separable 11-tap Gaussian (w2d = outer(g,g)) -> row pass + col pass.
//  - 5 convolved quantities computed fused per tile: p, t, p*p, t*t, p*t.
//  - Tile 64x16 outputs per 256-thread block; halo R=5 each side (zero pad,
//    matching lax.conv zero padding semantics).
//  - Deterministic 2-kernel reduction via d_ws (no atomics to d_out; harness
//    does not re-poison d_out between graph replays).

#define HH 512
#define WW 512
#define PLANES 48                 // 16 * 3
#define TW 64
#define TH 16
#define RR 5
#define KK 11
#define IN_W (TW + 2 * RR)        // 74
#define IN_H (TH + 2 * RR)        // 26
#define SP_STRIDE 76              // pad 74 -> 76 (keeps float4 alignment, 304B rows)
#define TILES_X (WW / TW)         // 8
#define TILES_Y (HH / TH)         // 32
#define NBLOCKS (PLANES * TILES_X * TILES_Y)  // 12288
#define NTHREADS 256
#define TOTAL_ELEMS (PLANES * HH * WW)        // 12582912

__device__ __constant__ float G_[KK] = {
    1.4867195147342977e-06f, 1.3383022576488537e-04f, 4.4318484119380075e-03f,
    5.3990966513188063e-02f, 2.4197072451914337e-01f, 3.9894228040143270e-01f,
    2.4197072451914337e-01f, 5.3990966513188063e-02f, 4.4318484119380075e-03f,
    1.3383022576488537e-04f, 1.4867195147342977e-06f};

__global__ __launch_bounds__(NTHREADS) void ssim_tile_kernel(
    const float* __restrict__ pred, const float* __restrict__ targ,
    float* __restrict__ partial) {
  __shared__ __align__(16) float sp[IN_H][SP_STRIDE];
  __shared__ __align__(16) float st[IN_H][SP_STRIDE];
  __shared__ __align__(16) float rb[5][IN_H][TW];
  __shared__ float wsums[4];

  const int tid = threadIdx.x;
  const int bid = blockIdx.x;
  const int plane = bid >> 8;          // / 256 tiles-per-plane
  const int tile = bid & 255;
  const int x0 = (tile & 7) * TW;
  const int y0 = (tile >> 3) * TH;
  const float* pp = pred + (size_t)plane * (HH * WW);
  const float* tp = targ + (size_t)plane * (HH * WW);

  // ---- Stage 0: load halo tile (zero-padded) ----
  for (int i = tid; i < IN_H * IN_W; i += NTHREADS) {
    int r = i / IN_W;
    int c = i - r * IN_W;
    int gy = y0 + r - RR;
    int gx = x0 + c - RR;
    float pv = 0.f, tv = 0.f;
    if (gy >= 0 && gy < HH && gx >= 0 && gx < WW) {
      int gidx = gy * WW + gx;
      pv = pp[gidx];
      tv = tp[gidx];
    }
    sp[r][c] = pv;
    st[r][c] = tv;
  }
  __syncthreads();

  // ---- Stage 1: row convolution of 5 quantities (4 outputs / item) ----
  // items: 26 rows x 16 col-groups = 416
  for (int i = tid; i < IN_H * (TW / 4); i += NTHREADS) {
    int r = i >> 4;
    int c4 = (i & 15) * 4;
    float p[16], t[16];
    const float4* sp4 = reinterpret_cast<const float4*>(&sp[r][c4]);
    const float4* st4 = reinterpret_cast<const float4*>(&st[r][c4]);
#pragma unroll
    for (int u = 0; u < 4; ++u) {
      float4 a = sp4[u];
      float4 b = st4[u];
      p[4 * u + 0] = a.x; p[4 * u + 1] = a.y; p[4 * u + 2] = a.z; p[4 * u + 3] = a.w;
      t[4 * u + 0] = b.x; t[4 * u + 1] = b.y; t[4 * u + 2] = b.z; t[4 * u + 3] = b.w;
    }
    float s[5][4];
#pragma unroll
    for (int q = 0; q < 5; ++q)
#pragma unroll
      for (int j = 0; j < 4; ++j) s[q][j] = 0.f;
#pragma unroll
    for (int j = 0; j < 4; ++j) {
#pragma unroll
      for (int k = 0; k < KK; ++k) {
        float w = G_[k];
        float pv = p[j + k];
        float tv = t[j + k];
        float wp = w * pv;
        float wt = w * tv;
        s[0][j] = fmaf(w, pv, s[0][j]);
        s[1][j] = fmaf(w, tv, s[1][j]);
        s[2][j] = fmaf(wp, pv, s[2][j]);
        s[3][j] = fmaf(wt, tv, s[3][j]);
        s[4][j] = fmaf(wp, tv, s[4][j]);
      }
    }
#pragma unroll
    for (int q = 0; q < 5; ++q) {
      float4 v = make_float4(s[q][0], s[q][1], s[q][2], s[q][3]);
      *reinterpret_cast<float4*>(&rb[q][r][c4]) = v;
    }
  }
  __syncthreads();

  // ---- Stage 2: column convolution + SSIM map (4 vertical outputs/thread) ----
  float lsum = 0.f;
  {
    const int x = tid & 63;
    const int ybase = (tid >> 6) * 4;  // 0,4,8,12
    float s[5][4];
#pragma unroll
    for (int q = 0; q < 5; ++q) {
      float rv[14];
#pragma unroll
      for (int m = 0; m < 14; ++m) rv[m] = rb[q][ybase + m][x];
#pragma unroll
      for (int j = 0; j < 4; ++j) {
        float acc = 0.f;
#pragma unroll
        for (int k = 0; k < KK; ++k) acc = fmaf(G_[k], rv[j + k], acc);
        s[q][j] = acc;
      }
    }
    const float C1 = 1.0e-4f;  // (0.01*1)^2
    const float C2 = 9.0e-4f;  // (0.03*1)^2
#pragma unroll
    for (int j = 0; j < 4; ++j) {
      float mu_x = s[0][j];
      float mu_y = s[1][j];
      float sxx = s[2][j] - mu_x * mu_x;
      float syy = s[3][j] - mu_y * mu_y;
      float sxy = s[4][j] - mu_x * mu_y;
      float num = (2.f * mu_x * mu_y + C1) * (2.f * sxy + C2);
      float den = (mu_x * mu_x + mu_y * mu_y + C1) *
                  (sxx * sxx + syy * syy + C2);
      lsum += num / den;
    }
  }

  // ---- Block reduction -> partial[bid] ----
#pragma unroll
  for (int off = 32; off > 0; off >>= 1) lsum += __shfl_xor(lsum, off, 64);
  if ((tid & 63) == 0) wsums[tid >> 6] = lsum;
  __syncthreads();
  if (tid == 0)
    partial[bid] = (wsums[0] + wsums[1]) + (wsums[2] + wsums[3]);
}

__global__ __launch_bounds__(1024) void ssim_reduce_kernel(
    const float* __restrict__ partial, float* __restrict__ out) {
  float s = 0.f;
  for (int i = threadIdx.x; i < NBLOCKS; i += 1024) s += partial[i];
#pragma unroll
  for (int off = 32; off > 0; off >>= 1) s += __shfl_xor(s, off, 64);
  __shared__ float ws[16];
  if ((threadIdx.x & 63) == 0) ws[threadIdx.x >> 6] = s;
  __syncthreads();
  if (threadIdx.x == 0) {
    float t = 0.f;
#pragma unroll
    for (int i = 0; i < 16; ++i) t += ws[i];
    out[0] = t * (1.0f / (float)TOTAL_ELEMS);
  }
}

extern "C" void kernel_launch(void* const* d_in, const int* in_sizes, int n_in,
                              void* d_out, int out_size, void* d_ws,
                              size_t ws_size, hipStream_t stream) {
  const float* pred = (const float*)d_in[0];
  const float* targ = (const float*)d_in[1];
  float* out = (float*)d_out;
  float* partial = (float*)d_ws;  // needs 12288 * 4 = 48 KiB

  ssim_tile_kernel<<<NBLOCKS, NTHREADS, 0, stream>>>(pred, targ, partial);
  ssim_reduce_kernel<<<1, 1024, 0, stream>>>(partial, out);
}

// Round 2
// 112.173 us; speedup vs baseline: 1.1447x; 1.1447x over previous
//
#include <hip/hip_runtime.h>

// SSIM fused kernel v2, MI355X (gfx950).
// Changes vs v1:
//  - Removed LDS input staging + its barrier: row conv loads pred/target
//    directly from global (aligned float4 fast path for interior tiles;
//    tile working set ~15 KB is L1-resident, so amplification is L1-served).
//  - LDS = rb only (33.4 KB) -> 4 blocks/CU (was 3 at 49 KB).
//  - Squares/products computed once per window element (42 muls) instead of
//    2 muls per tap (88).
//  - Precise fdiv -> v_rcp_f32 (rel err ~1e-7, threshold is 2.6e-3).

#define HH 512
#define WW 512
#define PLANES 48                 // 16 * 3
#define TW 64
#define TH 16
#define RR 5
#define KK 11
#define IN_H (TH + 2 * RR)        // 26
#define TILES_X (WW / TW)         // 8
#define TILES_Y (HH / TH)         // 32
#define NBLOCKS (PLANES * TILES_X * TILES_Y)  // 12288
#define NTHREADS 256
#define NITEMS (IN_H * (TW / 4))  // 416 row-conv items (row, 4-col group)
#define TOTAL_ELEMS (PLANES * HH * WW)        // 12582912

__device__ __constant__ float G_[KK] = {
    1.4867195147342977e-06f, 1.3383022576488537e-04f, 4.4318484119380075e-03f,
    5.3990966513188063e-02f, 2.4197072451914337e-01f, 3.9894228040143270e-01f,
    2.4197072451914337e-01f, 5.3990966513188063e-02f, 4.4318484119380075e-03f,
    1.3383022576488537e-04f, 1.4867195147342977e-06f};

__global__ __launch_bounds__(NTHREADS, 4) void ssim_tile_kernel(
    const float* __restrict__ pred, const float* __restrict__ targ,
    float* __restrict__ partial) {
  // rb[q][r][x]: row-conv results for 5 quantities, 26 halo rows x 64 cols.
  // Stage-1 writes: quarter-wave = 16 lanes = one row = 64 consecutive
  // floats = 2 lanes/bank (free). Stage-2 reads: 64 consecutive floats
  // across the wave (free). No padding needed.
  __shared__ __align__(16) float rb[5][IN_H][TW];
  __shared__ float wsums[4];

  const int tid = threadIdx.x;
  const int bid = blockIdx.x;
  const int plane = bid >> 8;          // 256 tiles per plane
  const int tile = bid & 255;
  const int x0 = (tile & 7) * TW;
  const int y0 = (tile >> 3) * TH;
  const float* pp = pred + (size_t)plane * (HH * WW);
  const float* tp = targ + (size_t)plane * (HH * WW);

  // Interior tile: every load in [x0-8, x0+71] x [y0-5, y0+20] is in-range.
  const bool interior = (x0 >= 64) && (x0 <= 384) && (y0 >= 16) && (y0 <= 480);

  // ---- Stage 1: row convolution of 5 quantities, direct from global ----
  for (int i = tid; i < NITEMS; i += NTHREADS) {
    const int r = i >> 4;              // 0..25 halo row
    const int c4 = (i & 15) << 2;      // 0..60 output col group
    const int gy = y0 + r - RR;

    // window: global cols x0+c4-8 .. x0+c4+11 (20 floats, 16B-aligned start)
    // needed: j = 3..16  (output col j0=0..3, tap k: idx = j0+k+3)
    float pw[20], tw[20];
    if (interior) {
      const float* prow = pp + gy * WW + (x0 + c4 - 8);
      const float* trow = tp + gy * WW + (x0 + c4 - 8);
#pragma unroll
      for (int u = 0; u < 5; ++u) {
        float4 a = reinterpret_cast<const float4*>(prow)[u];
        float4 b = reinterpret_cast<const float4*>(trow)[u];
        pw[4 * u + 0] = a.x; pw[4 * u + 1] = a.y;
        pw[4 * u + 2] = a.z; pw[4 * u + 3] = a.w;
        tw[4 * u + 0] = b.x; tw[4 * u + 1] = b.y;
        tw[4 * u + 2] = b.z; tw[4 * u + 3] = b.w;
      }
    } else {
      if (gy >= 0 && gy < HH) {
        const float* prow = pp + gy * WW;
        const float* trow = tp + gy * WW;
#pragma unroll
        for (int j = 3; j <= 16; ++j) {
          int gx = x0 + c4 - 8 + j;
          bool ok = (gx >= 0) && (gx < WW);
          pw[j] = ok ? prow[gx] : 0.f;
          tw[j] = ok ? trow[gx] : 0.f;
        }
      } else {
#pragma unroll
        for (int j = 3; j <= 16; ++j) { pw[j] = 0.f; tw[j] = 0.f; }
      }
    }

    // products once per window element (14 needed positions)
    float ppw[14], ttw[14], ptw[14];
#pragma unroll
    for (int j = 0; j < 14; ++j) {
      float a = pw[j + 3], b = tw[j + 3];
      ppw[j] = a * a;
      ttw[j] = b * b;
      ptw[j] = a * b;
    }

    float s[5][4];
#pragma unroll
    for (int q = 0; q < 5; ++q)
#pragma unroll
      for (int j = 0; j < 4; ++j) s[q][j] = 0.f;
#pragma unroll
    for (int j = 0; j < 4; ++j) {
#pragma unroll
      for (int k = 0; k < KK; ++k) {
        const float w = G_[k];
        const int idx = j + k;  // 0..13
        s[0][j] = fmaf(w, pw[idx + 3], s[0][j]);
        s[1][j] = fmaf(w, tw[idx + 3], s[1][j]);
        s[2][j] = fmaf(w, ppw[idx], s[2][j]);
        s[3][j] = fmaf(w, ttw[idx], s[3][j]);
        s[4][j] = fmaf(w, ptw[idx], s[4][j]);
      }
    }
#pragma unroll
    for (int q = 0; q < 5; ++q) {
      *reinterpret_cast<float4*>(&rb[q][r][c4]) =
          make_float4(s[q][0], s[q][1], s[q][2], s[q][3]);
    }
  }
  __syncthreads();

  // ---- Stage 2: column convolution + SSIM map (4 vertical outputs/thread) --
  float lsum = 0.f;
  {
    const int x = tid & 63;
    const int ybase = (tid >> 6) * 4;  // 0,4,8,12
    float s[5][4];
#pragma unroll
    for (int q = 0; q < 5; ++q) {
      float rv[14];
#pragma unroll
      for (int m = 0; m < 14; ++m) rv[m] = rb[q][ybase + m][x];
#pragma unroll
      for (int j = 0; j < 4; ++j) {
        float acc = 0.f;
#pragma unroll
        for (int k = 0; k < KK; ++k) acc = fmaf(G_[k], rv[j + k], acc);
        s[q][j] = acc;
      }
    }
    const float C1 = 1.0e-4f;  // (0.01*1)^2
    const float C2 = 9.0e-4f;  // (0.03*1)^2
#pragma unroll
    for (int j = 0; j < 4; ++j) {
      float mu_x = s[0][j];
      float mu_y = s[1][j];
      float sxx = s[2][j] - mu_x * mu_x;
      float syy = s[3][j] - mu_y * mu_y;
      float sxy = s[4][j] - mu_x * mu_y;
      float num = (2.f * mu_x * mu_y + C1) * (2.f * sxy + C2);
      float den = (mu_x * mu_x + mu_y * mu_y + C1) *
                  (sxx * sxx + syy * syy + C2);
      lsum = fmaf(num, __builtin_amdgcn_rcpf(den), lsum);
    }
  }

  // ---- Block reduction -> partial[bid] ----
#pragma unroll
  for (int off = 32; off > 0; off >>= 1) lsum += __shfl_xor(lsum, off, 64);
  if ((tid & 63) == 0) wsums[tid >> 6] = lsum;
  __syncthreads();
  if (tid == 0)
    partial[bid] = (wsums[0] + wsums[1]) + (wsums[2] + wsums[3]);
}

__global__ __launch_bounds__(1024) void ssim_reduce_kernel(
    const float* __restrict__ partial, float* __restrict__ out) {
  float s = 0.f;
  for (int i = threadIdx.x; i < NBLOCKS; i += 1024) s += partial[i];
#pragma unroll
  for (int off = 32; off > 0; off >>= 1) s += __shfl_xor(s, off, 64);
  __shared__ float ws[16];
  if ((threadIdx.x & 63) == 0) ws[threadIdx.x >> 6] = s;
  __syncthreads();
  if (threadIdx.x == 0) {
    float t = 0.f;
#pragma unroll
    for (int i = 0; i < 16; ++i) t += ws[i];
    out[0] = t * (1.0f / (float)TOTAL_ELEMS);
  }
}

extern "C" void kernel_launch(void* const* d_in, const int* in_sizes, int n_in,
                              void* d_out, int out_size, void* d_ws,
                              size_t ws_size, hipStream_t stream) {
  const float* pred = (const float*)d_in[0];
  const float* targ = (const float*)d_in[1];
  float* out = (float*)d_out;
  float* partial = (float*)d_ws;  // 12288 * 4 = 48 KiB of d_ws

  ssim_tile_kernel<<<NBLOCKS, NTHREADS, 0, stream>>>(pred, targ, partial);
  ssim_reduce_kernel<<<1, 1024, 0, stream>>>(partial, out);
}